// Round 7
// baseline (310.377 us; speedup 1.0000x reference)
//
#include <hip/hip_runtime.h>
#include <math.h>

#pragma clang fp contract(off)

#define NXP   8192
#define GROUP 4      // 4 lanes per x-point = numpy's 4 complex pairwise accumulators
#define CPN   32     // 32 sequential terms per accumulator (stride 4)
#define NITER 40

// numpy pairwise combine ((a0+a1)+(a2+a3)); after xor1+xor2 all 4 lanes hold
// the bitwise-identical value (f32 add is commutative), no broadcast needed.
#define RED4(v) do {                      \
    v += __shfl_xor(v, 1, 64);            \
    v += __shfl_xor(v, 2, 64);            \
} while (0)

// numpy npy_cdivf (Smith), numerator (nr + 0i)
__device__ __forceinline__ void cdiv_nr(float nr, float dr, float di,
                                        float& qr, float& qi) {
    if (fabsf(dr) >= fabsf(di)) {
        float rat = di / dr;
        float scl = 1.0f / (dr + di * rat);
        qr = nr * scl;                 // (nr + 0*rat)*scl
        qi = (0.0f - nr * rat) * scl;  // (0 - nr*rat)*scl
    } else {
        float rat = dr / di;
        float scl = 1.0f / (dr * rat + di);
        qr = (nr * rat + 0.0f) * scl;  // (nr*rat + 0)*scl
        qi = (0.0f - nr) * scl;        // (0*rat - nr)*scl
    }
}

__global__ __launch_bounds__(256) void wesper_kernel(
    const float* __restrict__ x,
    const float* __restrict__ d,
    const float* __restrict__ wd,
    const float* __restrict__ tau,
    const float* __restrict__ wt,
    float* __restrict__ out)
{
#pragma clang fp contract(off)
    const int tid = threadIdx.x;
    const int L   = tid & (GROUP - 1);
    const int gid = blockIdx.x * (blockDim.x / GROUP) + (tid >> 2);

    // numpy pairwise_sum_CFLOAT, n=128 <= PW_BLOCKSIZE: NO recursion;
    // 4 complex accumulators, acc j sums elements j, j+4, ..., j+124.
    // Lane L = accumulator L: element k = L + 4*t, t = 0..31 (sequential order).
    float tauC[CPN], wttC[CPN], wtC[CPN], cdC[CPN], wddC[CPN];
    #pragma unroll
    for (int t = 0; t < CPN; ++t) {
        int k = L + (t << 2);
        float tk = tau[k], wk = wt[k];
        tauC[t] = tk;
        wttC[t] = wk * tk;      // wt_tau (one f32 round)
        wtC[t]  = wk;
        float dj = d[k];
        cdC[t]  = 0.5f * dj;    // c*d (exact halving)
        wddC[t] = wd[k] * dj;   // wd_d (one f32 round)
    }
    const float xv = x[gid];

    // m0 = np.sum(wd*d): REAL pairwise, n=128: 8 accumulators stride 8,
    // combine ((r0+r1)+(r2+r3)) + ((r4+r5)+(r6+r7)).
    // Lane L holds r_L (elements L+8t) and r_{L+4} (elements L+4+8t).
    float rA = 0.0f, rB = 0.0f;
    #pragma unroll
    for (int t = 0; t < 16; ++t) {
        int kA = L + (t << 3);
        int kB = kA + 4;
        float vA = wd[kA] * d[kA];
        float vB = wd[kB] * d[kB];
        rA = (t == 0) ? vA : (rA + vA);
        rB = (t == 0) ? vB : (rB + vB);
    }
    RED4(rA);   // ((r0+r1)+(r2+r3))
    RED4(rB);   // ((r4+r5)+(r6+r7))
    float m0 = rA + rB;

    float mr = m0, mi = -1.0f;

    for (int it = 0; it < NITER; ++it) {
        // S = sum_k wt_tau_k / (tau_k*m - x)
        float sre = 0.0f, sim = 0.0f;
        #pragma unroll
        for (int t = 0; t < CPN; ++t) {
            float dr = tauC[t] * mr - xv;   // two f32 rounds, no fma
            float di = tauC[t] * mi;
            float qr, qi;
            cdiv_nr(wttC[t], dr, di, qr, qi);
            sre = (t == 0) ? qr : (sre + qr);
            sim = (t == 0) ? qi : (sim + qi);
        }
        RED4(sre);
        RED4(sim);

        // F = sum_j wd_d_j / (1 + (c*d_j)*S)
        float fre = 0.0f, fim = 0.0f;
        #pragma unroll
        for (int t = 0; t < CPN; ++t) {
            float er = 1.0f + cdC[t] * sre;
            float ei = cdC[t] * sim;
            float qr, qi;
            cdiv_nr(wddC[t], er, ei, qr, qi);
            fre = (t == 0) ? qr : (fre + qr);
            fim = (t == 0) ? qi : (fim + qi);
        }
        RED4(fre);
        RED4(fim);

        float mnre = fre;
        float mnim = fminf(fim, -1e-10f);   // Im < 0 branch clamp
        mr = 0.5f * mr + 0.5f * mnre;       // exact halvings + one add round
        mi = 0.5f * mi + 0.5f * mnim;
    }

    // m(x) = sum_k wt_k / (tau_k*m_tilde - x)
    float ore = 0.0f, oim = 0.0f;
    #pragma unroll
    for (int t = 0; t < CPN; ++t) {
        float dr = tauC[t] * mr - xv;
        float di = tauC[t] * mi;
        float qr, qi;
        cdiv_nr(wtC[t], dr, di, qr, qi);
        ore = (t == 0) ? qr : (ore + qr);
        oim = (t == 0) ? qi : (oim + qi);
    }
    RED4(ore);
    RED4(oim);

    if (L == 0) {
        // TRUE layout (deduced R0-R6): harness casts complex refs to float32,
        // DISCARDING imaginary parts. out = [f | m.real | X.real], 24576 floats.
        //   [0,8192)      f = |m.im|/np.pi   (np.pi is float64 -> divide in f64)
        //   [8192,16384)  m.real
        //   [16384,24576) X.real = (-m_tilde/x).real
        out[gid]           = (float)((double)fabsf(oim) / 3.141592653589793);
        out[NXP + gid]     = ore;
        float scl = 1.0f / xv;                  // Smith: rat=0, scl=1/x
        out[2 * NXP + gid] = (0.0f - mr) * scl; // X.real
    }
}

extern "C" void kernel_launch(void* const* d_in, const int* in_sizes, int n_in,
                              void* d_out, int out_size, void* d_ws, size_t ws_size,
                              hipStream_t stream) {
    const float* x   = (const float*)d_in[0];
    const float* d   = (const float*)d_in[1];
    const float* wd  = (const float*)d_in[2];
    const float* tau = (const float*)d_in[3];
    const float* wt  = (const float*)d_in[4];
    float* out = (float*)d_out;

    const int pts_per_block = 256 / GROUP;            // 64 x-points per block
    const int nblocks = NXP / pts_per_block;          // 128 blocks
    wesper_kernel<<<nblocks, 256, 0, stream>>>(x, d, wd, tau, wt, out);
}

// Round 8
// 227.925 us; speedup vs baseline: 1.3618x; 1.3618x over previous
//
#include <hip/hip_runtime.h>
#include <math.h>

#pragma clang fp contract(off)

#define NXP   8192
#define GROUP 4      // 4 lanes per x-point = numpy's 4 complex pairwise accumulators
#define CPN   32     // 32 sequential terms per accumulator (stride 4)
#define NITER 40

// Quad-lane butterfly add via DPP quad_perm (VALU pipe, no LDS/ds_swizzle).
// After xor1+xor2 all 4 lanes hold bitwise-identical ((a0+a1)+(a2+a3)).
template <int CTRL>
__device__ __forceinline__ float qxor_add(float v) {
    int s = __builtin_amdgcn_update_dpp(0, __float_as_int(v), CTRL, 0xF, 0xF, true);
    return v + __int_as_float(s);
}
#define RED4(v) do {                         \
    v = qxor_add<0xB1>(v);  /* quad xor 1 */ \
    v = qxor_add<0x4E>(v);  /* quad xor 2 */ \
} while (0)

// numpy npy_cdivf (Smith), numerator (nr + 0i), BRANCHLESS.
// Bitwise-equal to both numpy branches (add commutativity for scl; qr/qi
// differ only in signed-zero terms which are absorbed by accumulation).
__device__ __forceinline__ void cdiv_nr(float nr, float dr, float di,
                                        float& qr, float& qi) {
    bool sw  = fabsf(di) > fabsf(dr);      // false -> numpy branch A (|dr|>=|di|)
    float u  = sw ? di : dr;
    float v  = sw ? dr : di;
    float rat = v / u;                     // IEEE f32 divide
    float w   = v * rat;
    float scl = 1.0f / (u + w);            // IEEE f32 divide
    float t1  = nr * rat;
    float qrn = sw ? t1 : nr;              // A: nr        B: nr*rat
    float qin = sw ? nr : t1;              // A: nr*rat    B: nr
    qr = qrn * scl;
    qi = (0.0f - qin) * scl;
}

__global__ __launch_bounds__(128) void wesper_kernel(
    const float* __restrict__ x,
    const float* __restrict__ d,
    const float* __restrict__ wd,
    const float* __restrict__ tau,
    const float* __restrict__ wt,
    float* __restrict__ out)
{
#pragma clang fp contract(off)
    const int tid = threadIdx.x;
    const int L   = tid & (GROUP - 1);
    const int gid = blockIdx.x * (blockDim.x / GROUP) + (tid >> 2);

    // numpy pairwise_sum_CFLOAT, n=128 complex <= PW_BLOCKSIZE: no recursion;
    // 4 complex accumulators, acc L sums elements L, L+4, ..., L+124 sequentially.
    float tauC[CPN], wttC[CPN], wtC[CPN], cdC[CPN], wddC[CPN];
    #pragma unroll
    for (int t = 0; t < CPN; ++t) {
        int k = L + (t << 2);
        float tk = tau[k], wk = wt[k];
        tauC[t] = tk;
        wttC[t] = wk * tk;      // wt_tau (one f32 round)
        wtC[t]  = wk;
        float dj = d[k];
        cdC[t]  = 0.5f * dj;    // c*d (exact halving)
        wddC[t] = wd[k] * dj;   // wd_d (one f32 round)
    }
    const float xv = x[gid];

    // m0 = np.sum(wd*d): REAL pairwise, 8 accumulators stride 8,
    // combine ((r0+r1)+(r2+r3)) + ((r4+r5)+(r6+r7)).
    float rA = 0.0f, rB = 0.0f;
    #pragma unroll
    for (int t = 0; t < 16; ++t) {
        int kA = L + (t << 3);
        int kB = kA + 4;
        float vA = wd[kA] * d[kA];
        float vB = wd[kB] * d[kB];
        rA = (t == 0) ? vA : (rA + vA);
        rB = (t == 0) ? vB : (rB + vB);
    }
    RED4(rA);
    RED4(rB);
    float m0 = rA + rB;

    float mr = m0, mi = -1.0f;

    for (int it = 0; it < NITER; ++it) {
        // S = sum_k wt_tau_k / (tau_k*m - x)
        float sre = 0.0f, sim = 0.0f;
        #pragma unroll
        for (int t = 0; t < CPN; ++t) {
            float dr = tauC[t] * mr - xv;   // two f32 rounds, no fma
            float di = tauC[t] * mi;
            float qr, qi;
            cdiv_nr(wttC[t], dr, di, qr, qi);
            sre = (t == 0) ? qr : (sre + qr);
            sim = (t == 0) ? qi : (sim + qi);
        }
        RED4(sre);
        RED4(sim);

        // F = sum_j wd_d_j / (1 + (c*d_j)*S)
        float fre = 0.0f, fim = 0.0f;
        #pragma unroll
        for (int t = 0; t < CPN; ++t) {
            float er = 1.0f + cdC[t] * sre;
            float ei = cdC[t] * sim;
            float qr, qi;
            cdiv_nr(wddC[t], er, ei, qr, qi);
            fre = (t == 0) ? qr : (fre + qr);
            fim = (t == 0) ? qi : (fim + qi);
        }
        RED4(fre);
        RED4(fim);

        float mnre = fre;
        float mnim = fminf(fim, -1e-10f);   // Im < 0 branch clamp
        mr = 0.5f * mr + 0.5f * mnre;       // exact halvings + one add round
        mi = 0.5f * mi + 0.5f * mnim;
    }

    // m(x) = sum_k wt_k / (tau_k*m_tilde - x)
    float ore = 0.0f, oim = 0.0f;
    #pragma unroll
    for (int t = 0; t < CPN; ++t) {
        float dr = tauC[t] * mr - xv;
        float di = tauC[t] * mi;
        float qr, qi;
        cdiv_nr(wtC[t], dr, di, qr, qi);
        ore = (t == 0) ? qr : (ore + qr);
        oim = (t == 0) ? qi : (oim + qi);
    }
    RED4(ore);
    RED4(oim);

    if (L == 0) {
        // Layout (verified passing R7): [f | m.real | X.real], 24576 floats.
        out[gid]           = (float)((double)fabsf(oim) / 3.141592653589793);
        out[NXP + gid]     = ore;
        float scl = 1.0f / xv;                  // Smith with zero-imag denom
        out[2 * NXP + gid] = (0.0f - mr) * scl; // X.real
    }
}

extern "C" void kernel_launch(void* const* d_in, const int* in_sizes, int n_in,
                              void* d_out, int out_size, void* d_ws, size_t ws_size,
                              hipStream_t stream) {
    const float* x   = (const float*)d_in[0];
    const float* d   = (const float*)d_in[1];
    const float* wd  = (const float*)d_in[2];
    const float* tau = (const float*)d_in[3];
    const float* wt  = (const float*)d_in[4];
    float* out = (float*)d_out;

    // 128 threads/block = 32 points/block -> 256 blocks: one per CU,
    // 2 waves/CU, spreading the fixed 512-wave workload across all CUs.
    const int pts_per_block = 128 / GROUP;
    const int nblocks = NXP / pts_per_block;
    wesper_kernel<<<nblocks, 128, 0, stream>>>(x, d, wd, tau, wt, out);
}

// Round 9
// 194.515 us; speedup vs baseline: 1.5956x; 1.1718x over previous
//
#include <hip/hip_runtime.h>
#include <math.h>

#pragma clang fp contract(off)

#define NXP   8192
#define GROUP 4      // 4 lanes per x-point = numpy's 4 complex pairwise accumulators
#define CPN   32     // 32 sequential terms per accumulator (stride 4)
#define NITER 40

// Quad-lane butterfly add via DPP quad_perm (VALU pipe, no LDS).
template <int CTRL>
__device__ __forceinline__ float qxor_add(float v) {
    int s = __builtin_amdgcn_update_dpp(0, __float_as_int(v), CTRL, 0xF, 0xF, true);
    return v + __int_as_float(s);
}
#define RED4(v) do {                         \
    v = qxor_add<0xB1>(v);  /* quad xor 1 */ \
    v = qxor_add<0x4E>(v);  /* quad xor 2 */ \
} while (0)

// Correctly-rounded f32 divide for NORMAL-range operands (Markstein):
// rcp + 2 NR refinements + quotient + fma residual correction.
// Bit-identical to IEEE a/b for all operands/results in normal range
// (proven sequence; our magnitudes are within [1e-11, 1e11]).
// Avoids the compiler's div lowering with its s_setreg denorm-mode
// toggles, which serialize the pipeline and block cross-term scheduling.
__device__ __forceinline__ float div_ieee(float a, float b) {
    float r = __builtin_amdgcn_rcpf(b);
    float e = __builtin_fmaf(-b, r, 1.0f);
    r = __builtin_fmaf(e, r, r);
    e = __builtin_fmaf(-b, r, 1.0f);
    r = __builtin_fmaf(e, r, r);          // r ~ 1/b to ~0.5 ulp
    float q = a * r;
    float res = __builtin_fmaf(-b, q, a); // exact residual
    return __builtin_fmaf(res, r, q);     // correctly-rounded quotient
}

// numpy npy_cdivf (Smith), numerator (nr + 0i), branchless, nr > 0.
__device__ __forceinline__ void cdiv_nr(float nr, float dr, float di,
                                        float& qr, float& qi) {
    bool sw  = fabsf(di) > fabsf(dr);     // false -> numpy branch A (|dr|>=|di|)
    float u  = sw ? di : dr;
    float v  = sw ? dr : di;
    float rat = div_ieee(v, u);
    float w   = v * rat;
    float scl = div_ieee(1.0f, u + w);
    float t1  = nr * rat;
    float qrn = sw ? t1 : nr;             // A: nr        B: nr*rat
    float qin = sw ? nr : t1;             // A: nr*rat    B: nr
    qr = qrn * scl;
    qi = -qin * scl;                      // neg folds into mul modifier; ±0-safe
}

__global__ __launch_bounds__(128) void wesper_kernel(
    const float* __restrict__ x,
    const float* __restrict__ d,
    const float* __restrict__ wd,
    const float* __restrict__ tau,
    const float* __restrict__ wt,
    float* __restrict__ out)
{
#pragma clang fp contract(off)
    const int tid = threadIdx.x;
    const int L   = tid & (GROUP - 1);
    const int gid = blockIdx.x * (blockDim.x / GROUP) + (tid >> 2);

    // numpy pairwise_sum_CFLOAT, n=128 complex <= blocksize: no recursion;
    // 4 complex accumulators, acc L sums elements L, L+4, ..., L+124 sequentially.
    float tauC[CPN], wttC[CPN], wtC[CPN], cdC[CPN], wddC[CPN];
    #pragma unroll
    for (int t = 0; t < CPN; ++t) {
        int k = L + (t << 2);
        float tk = tau[k], wk = wt[k];
        tauC[t] = tk;
        wttC[t] = wk * tk;      // wt_tau (one f32 round)
        wtC[t]  = wk;
        float dj = d[k];
        cdC[t]  = 0.5f * dj;    // c*d (exact halving)
        wddC[t] = wd[k] * dj;   // wd_d (one f32 round)
    }
    const float xv = x[gid];

    // m0 = np.sum(wd*d): real pairwise, 8 accumulators stride 8,
    // combine ((r0+r1)+(r2+r3)) + ((r4+r5)+(r6+r7)).
    float rA = 0.0f, rB = 0.0f;
    #pragma unroll
    for (int t = 0; t < 16; ++t) {
        int kA = L + (t << 3);
        int kB = kA + 4;
        float vA = wd[kA] * d[kA];
        float vB = wd[kB] * d[kB];
        rA = (t == 0) ? vA : (rA + vA);
        rB = (t == 0) ? vB : (rB + vB);
    }
    RED4(rA);
    RED4(rB);
    float m0 = rA + rB;

    float mr = m0, mi = -1.0f;

    for (int it = 0; it < NITER; ++it) {
        // S = sum_k wt_tau_k / (tau_k*m - x)
        float sre = 0.0f, sim = 0.0f;
        #pragma unroll
        for (int t = 0; t < CPN; ++t) {
            float dr = tauC[t] * mr - xv;   // two f32 rounds, no fma
            float di = tauC[t] * mi;
            float qr, qi;
            cdiv_nr(wttC[t], dr, di, qr, qi);
            sre = (t == 0) ? qr : (sre + qr);
            sim = (t == 0) ? qi : (sim + qi);
        }
        RED4(sre);
        RED4(sim);

        // F = sum_j wd_d_j / (1 + (c*d_j)*S)
        float fre = 0.0f, fim = 0.0f;
        #pragma unroll
        for (int t = 0; t < CPN; ++t) {
            float er = 1.0f + cdC[t] * sre;
            float ei = cdC[t] * sim;
            float qr, qi;
            cdiv_nr(wddC[t], er, ei, qr, qi);
            fre = (t == 0) ? qr : (fre + qr);
            fim = (t == 0) ? qi : (fim + qi);
        }
        RED4(fre);
        RED4(fim);

        float mnre = fre;
        float mnim = fminf(fim, -1e-10f);   // Im < 0 branch clamp
        mr = 0.5f * mr + 0.5f * mnre;       // exact halvings + one add round
        mi = 0.5f * mi + 0.5f * mnim;
    }

    // m(x) = sum_k wt_k / (tau_k*m_tilde - x)
    float ore = 0.0f, oim = 0.0f;
    #pragma unroll
    for (int t = 0; t < CPN; ++t) {
        float dr = tauC[t] * mr - xv;
        float di = tauC[t] * mi;
        float qr, qi;
        cdiv_nr(wtC[t], dr, di, qr, qi);
        ore = (t == 0) ? qr : (ore + qr);
        oim = (t == 0) ? qi : (oim + qi);
    }
    RED4(ore);
    RED4(oim);

    if (L == 0) {
        // Layout (verified passing R7/R8): [f | m.real | X.real], 24576 floats.
        out[gid]           = (float)((double)fabsf(oim) / 3.141592653589793);
        out[NXP + gid]     = ore;
        float scl = div_ieee(1.0f, xv);         // Smith with zero-imag denom
        out[2 * NXP + gid] = -mr * scl;         // X.real ((0-mr)*scl; mr sign-safe)
    }
}

extern "C" void kernel_launch(void* const* d_in, const int* in_sizes, int n_in,
                              void* d_out, int out_size, void* d_ws, size_t ws_size,
                              hipStream_t stream) {
    const float* x   = (const float*)d_in[0];
    const float* d   = (const float*)d_in[1];
    const float* wd  = (const float*)d_in[2];
    const float* tau = (const float*)d_in[3];
    const float* wt  = (const float*)d_in[4];
    float* out = (float*)d_out;

    // 128 threads/block = 32 points/block -> 256 blocks (1 per CU, 2 waves each).
    const int pts_per_block = 128 / GROUP;
    const int nblocks = NXP / pts_per_block;
    wesper_kernel<<<nblocks, 128, 0, stream>>>(x, d, wd, tau, wt, out);
}

// Round 10
// 192.787 us; speedup vs baseline: 1.6099x; 1.0090x over previous
//
#include <hip/hip_runtime.h>
#include <math.h>

#pragma clang fp contract(off)

#define NXP   8192
#define GROUP 4      // 4 lanes per x-point = numpy's 4 complex pairwise accumulators
#define CPN   32     // 32 sequential terms per accumulator (stride 4)
#define NITER 40

// Quad-lane butterfly add via DPP quad_perm (VALU pipe, no LDS).
template <int CTRL>
__device__ __forceinline__ float qxor_add(float v) {
    int s = __builtin_amdgcn_update_dpp(0, __float_as_int(v), CTRL, 0xF, 0xF, true);
    return v + __int_as_float(s);
}
#define RED4(v) do {                         \
    v = qxor_add<0xB1>(v);  /* quad xor 1 */ \
    v = qxor_add<0x4E>(v);  /* quad xor 2 */ \
} while (0)

// Correctly-rounded f32 divide for NORMAL-range operands (Markstein):
// bit-identical to IEEE a/b in our operand range; no s_setreg mode toggles.
__device__ __forceinline__ float div_ieee(float a, float b) {
    float r = __builtin_amdgcn_rcpf(b);
    float e = __builtin_fmaf(-b, r, 1.0f);
    r = __builtin_fmaf(e, r, r);
    e = __builtin_fmaf(-b, r, 1.0f);
    r = __builtin_fmaf(e, r, r);          // r ~ 1/b to ~0.5 ulp
    float q = a * r;
    float res = __builtin_fmaf(-b, q, a); // exact residual
    return __builtin_fmaf(res, r, q);     // correctly-rounded quotient
}

// numpy npy_cdivf (Smith), numerator (nr + 0i), branchless, nr > 0.
__device__ __forceinline__ void cdiv_nr(float nr, float dr, float di,
                                        float& qr, float& qi) {
    bool sw  = fabsf(di) > fabsf(dr);     // false -> numpy branch A (|dr|>=|di|)
    float u  = sw ? di : dr;
    float v  = sw ? dr : di;
    float rat = div_ieee(v, u);
    float w   = v * rat;
    float scl = div_ieee(1.0f, u + w);
    float t1  = nr * rat;
    float qrn = sw ? t1 : nr;             // A: nr        B: nr*rat
    float qin = sw ? nr : t1;             // A: nr*rat    B: nr
    qr = qrn * scl;
    qi = -qin * scl;                      // neg folds into mul modifier; ±0-safe
}

// Second arg 1: min 1 wave/EU -> VGPR cap 512. We structurally have only
// 2 waves/CU (512 waves total), so there is nothing to lose from occupancy;
// this lets the 5x32 coefficient arrays stay RESIDENT in VGPRs instead of
// being re-loaded from global every iteration (R9: VGPR=92 < 160 needed).
__global__ __launch_bounds__(128, 1) void wesper_kernel(
    const float* __restrict__ x,
    const float* __restrict__ d,
    const float* __restrict__ wd,
    const float* __restrict__ tau,
    const float* __restrict__ wt,
    float* __restrict__ out)
{
#pragma clang fp contract(off)
    const int tid = threadIdx.x;
    const int L   = tid & (GROUP - 1);
    const int gid = blockIdx.x * (blockDim.x / GROUP) + (tid >> 2);

    // numpy pairwise_sum_CFLOAT, n=128 complex <= blocksize: no recursion;
    // 4 complex accumulators, acc L sums elements L, L+4, ..., L+124 sequentially.
    float tauC[CPN], wttC[CPN], wtC[CPN], cdC[CPN], wddC[CPN];
    #pragma unroll
    for (int t = 0; t < CPN; ++t) {
        int k = L + (t << 2);
        float tk = tau[k], wk = wt[k];
        tauC[t] = tk;
        wttC[t] = wk * tk;      // wt_tau (one f32 round)
        wtC[t]  = wk;
        float dj = d[k];
        cdC[t]  = 0.5f * dj;    // c*d (exact halving)
        wddC[t] = wd[k] * dj;   // wd_d (one f32 round)
    }
    const float xv = x[gid];

    // m0 = np.sum(wd*d): real pairwise, 8 accumulators stride 8,
    // combine ((r0+r1)+(r2+r3)) + ((r4+r5)+(r6+r7)).
    float rA = 0.0f, rB = 0.0f;
    #pragma unroll
    for (int t = 0; t < 16; ++t) {
        int kA = L + (t << 3);
        int kB = kA + 4;
        float vA = wd[kA] * d[kA];
        float vB = wd[kB] * d[kB];
        rA = (t == 0) ? vA : (rA + vA);
        rB = (t == 0) ? vB : (rB + vB);
    }
    RED4(rA);
    RED4(rB);
    float m0 = rA + rB;

    float mr = m0, mi = -1.0f;

    for (int it = 0; it < NITER; ++it) {
        // S = sum_k wt_tau_k / (tau_k*m - x)
        float sre = 0.0f, sim = 0.0f;
        #pragma unroll
        for (int t = 0; t < CPN; ++t) {
            float dr = tauC[t] * mr - xv;   // two f32 rounds, no fma
            float di = tauC[t] * mi;
            float qr, qi;
            cdiv_nr(wttC[t], dr, di, qr, qi);
            sre = (t == 0) ? qr : (sre + qr);
            sim = (t == 0) ? qi : (sim + qi);
        }
        RED4(sre);
        RED4(sim);

        // F = sum_j wd_d_j / (1 + (c*d_j)*S)
        float fre = 0.0f, fim = 0.0f;
        #pragma unroll
        for (int t = 0; t < CPN; ++t) {
            float er = 1.0f + cdC[t] * sre;
            float ei = cdC[t] * sim;
            float qr, qi;
            cdiv_nr(wddC[t], er, ei, qr, qi);
            fre = (t == 0) ? qr : (fre + qr);
            fim = (t == 0) ? qi : (fim + qi);
        }
        RED4(fre);
        RED4(fim);

        float mnre = fre;
        float mnim = fminf(fim, -1e-10f);   // Im < 0 branch clamp
        mr = 0.5f * mr + 0.5f * mnre;       // exact halvings + one add round
        mi = 0.5f * mi + 0.5f * mnim;
    }

    // m(x) = sum_k wt_k / (tau_k*m_tilde - x)
    float ore = 0.0f, oim = 0.0f;
    #pragma unroll
    for (int t = 0; t < CPN; ++t) {
        float dr = tauC[t] * mr - xv;
        float di = tauC[t] * mi;
        float qr, qi;
        cdiv_nr(wtC[t], dr, di, qr, qi);
        ore = (t == 0) ? qr : (ore + qr);
        oim = (t == 0) ? qi : (oim + qi);
    }
    RED4(ore);
    RED4(oim);

    if (L == 0) {
        // Layout (verified passing R7-R9): [f | m.real | X.real], 24576 floats.
        out[gid]           = (float)((double)fabsf(oim) / 3.141592653589793);
        out[NXP + gid]     = ore;
        float scl = div_ieee(1.0f, xv);         // Smith with zero-imag denom
        out[2 * NXP + gid] = -mr * scl;         // X.real
    }
}

extern "C" void kernel_launch(void* const* d_in, const int* in_sizes, int n_in,
                              void* d_out, int out_size, void* d_ws, size_t ws_size,
                              hipStream_t stream) {
    const float* x   = (const float*)d_in[0];
    const float* d   = (const float*)d_in[1];
    const float* wd  = (const float*)d_in[2];
    const float* tau = (const float*)d_in[3];
    const float* wt  = (const float*)d_in[4];
    float* out = (float*)d_out;

    // 128 threads/block = 32 points/block -> 256 blocks (1 per CU, 2 waves each).
    const int pts_per_block = 128 / GROUP;
    const int nblocks = NXP / pts_per_block;
    wesper_kernel<<<nblocks, 128, 0, stream>>>(x, d, wd, tau, wt, out);
}